// Round 8
// baseline (351.828 us; speedup 1.0000x reference)
//
#include <hip/hip_runtime.h>
#include <stdint.h>

typedef unsigned short ushort_t;

#define KK3 3
#define IC 32      // input capsules
#define IP 16      // input pose
#define OC 32      // output capsules
#define OP 16      // output pose
#define NI 288     // KK3*KK3*IC (im2col "i" dimension)
#define HH 12
#define WWW 12
#define NTOT 1152  // b*h*w
#define CQ 512     // OC*OP
#define EPSQ 1e-9f
#define RWAVES 4   // waves per route block (256 threads)
#define RSTEPS 36  // i-steps per lane: NI / 8 i-rows per step
#define NIP 144    // i-pairs (K-steps of 32 for the s0 GEMM)

typedef __attribute__((ext_vector_type(8))) short bf16x8;
typedef __attribute__((ext_vector_type(4))) float f32x4;

__device__ __forceinline__ float bf_lo(unsigned u) { return __uint_as_float(u << 16); }
__device__ __forceinline__ float bf_hi(unsigned u) { return __uint_as_float(u & 0xffff0000u); }
__device__ __forceinline__ ushort_t f2bf(float f) {
    unsigned u = __float_as_uint(f);
    return (ushort_t)((u + 0x7fffu + ((u >> 16) & 1u)) >> 16);   // RNE
}

// ---------------------------------------------------------------------------
// Kernel P: pack W (f32) -> bf16 in MFMA-B-fragment layout.
// Wp[ip][c][lane][8]: lane l of the 16x16x32 B-frag holds W rows cq=c*16+q
// (q = l&15) at k = (l>>4)*8 + j, where k<16 -> i=2*ip (p=k), k>=16 -> i=2*ip+1.
// grid = 144*32 blocks, 64 threads.
// ---------------------------------------------------------------------------
__global__ __launch_bounds__(64) void pack_kernel(
    const float* __restrict__ W, ushort_t* __restrict__ Wp)
{
    const int blk = blockIdx.x;          // ip*32 + c
    const int ip = blk >> 5;
    const int c = blk & 31;
    const int l = threadIdx.x;
    const int i = ip * 2 + ((l >> 5) & 1);
    const int p0 = ((l >> 4) & 1) * 8;
    const int q = l & 15;
    const float* src = W + (((size_t)(i * 32 + c) * 16 + p0) * 16 + q);
    union { ushort_t s[8]; uint4 u4; } o;
#pragma unroll
    for (int j = 0; j < 8; ++j) o.s[j] = f2bf(src[(size_t)j * 16]);
    *(uint4*)(Wp + ((size_t)blk * 64 + l) * 8) = o.u4;
}

// ---------------------------------------------------------------------------
// Kernel S: s0_pre[n][cq] = sum_i votes[n,i,cq]  (one MFMA GEMM, K=4608).
// grid = (72 px-tiles, 4 N-blocks of 128 cq), 64 threads (1 wave).
// A-frag: u[px][p] gathered from x with im2col (row px = l&15).
// Follows the m92-verified fragment convention; D: col=l&15, row=(l>>4)*4+r.
// ---------------------------------------------------------------------------
__global__ __launch_bounds__(64) void s0_gemm_kernel(
    const float* __restrict__ x, const ushort_t* __restrict__ Wp,
    float* __restrict__ s0_pre)
{
    const int l = threadIdx.x;
    const int pxt = blockIdx.x;          // 0..71
    const int cb = blockIdx.y * 8;       // base c-tile
    const int px = pxt * 16 + (l & 15);
    const int b = px / (HH * WWW);
    const int rem = px % (HH * WWW);
    const int y = rem / WWW;
    const int xx = rem % WWW;
    const int ioff = (l >> 5) & 1;
    const int p0 = ((l >> 4) & 1) * 8;

    f32x4 acc[8];
#pragma unroll
    for (int ct = 0; ct < 8; ++ct) acc[ct] = (f32x4){0.f, 0.f, 0.f, 0.f};

    for (int ip = 0; ip < NIP; ++ip) {
        const int i = ip * 2 + ioff;
        const int ky = i / (KK3 * IC);
        const int kx = (i / IC) % KK3;
        const int ic = i & (IC - 1);
        const int sy = y + ky - 1;
        const int sx = xx + kx - 1;
        union { ushort_t s[8]; bf16x8 v; } ua;
        if (sy >= 0 && sy < HH && sx >= 0 && sx < WWW) {
            const float* s = x + ((((size_t)b * HH + sy) * WWW + sx) * IC + ic) * IP + p0;
            const float4 v0 = *(const float4*)s;
            const float4 v1 = *(const float4*)(s + 4);
            ua.s[0] = f2bf(v0.x); ua.s[1] = f2bf(v0.y); ua.s[2] = f2bf(v0.z); ua.s[3] = f2bf(v0.w);
            ua.s[4] = f2bf(v1.x); ua.s[5] = f2bf(v1.y); ua.s[6] = f2bf(v1.z); ua.s[7] = f2bf(v1.w);
        } else {
#pragma unroll
            for (int j = 0; j < 8; ++j) ua.s[j] = 0;
        }
#pragma unroll
        for (int ct = 0; ct < 8; ++ct) {
            const bf16x8 bv = *(const bf16x8*)(Wp + (((size_t)ip * 32 + (cb + ct)) * 64 + l) * 8);
            acc[ct] = __builtin_amdgcn_mfma_f32_16x16x32_bf16(ua.v, bv, acc[ct], 0, 0, 0);
        }
    }

    const int prow = pxt * 16 + (l >> 4) * 4;
    const int q = l & 15;
#pragma unroll
    for (int ct = 0; ct < 8; ++ct)
#pragma unroll
        for (int r = 0; r < 4; ++r)
            s0_pre[(size_t)(prow + r) * CQ + (size_t)(cb + ct) * 16 + q] = acc[ct][r];
}

// ---------------------------------------------------------------------------
// Kernel A: votes[nl][i][c][q] (bf16) for one pixel chunk.  (unchanged, R7)
// ---------------------------------------------------------------------------
__global__ __launch_bounds__(128) void votes_kernel(
    const float* __restrict__ x, const float* __restrict__ Wg,
    ushort_t* __restrict__ votes, int nStart, int nCount)
{
    __shared__ float u_lds[64][IP];

    const int i = blockIdx.x;
    const int tileBase = blockIdx.y * 64;
    const int nC = min(64, nCount - tileBase);
    const int t = threadIdx.x;
    const int c = t >> 2;
    const int qq = t & 3;

    const int ky = i / (KK3 * IC);
    const int kx = (i / IC) % KK3;
    const int ic = i % IC;

    {
        const int nl = t >> 1;
        const int ph = (t & 1) * 8;
        if (nl < nC) {
            const int n = nStart + tileBase + nl;
            const int b = n / (HH * WWW);
            const int rem = n % (HH * WWW);
            const int y = rem / WWW;
            const int xx = rem % WWW;
            const int sy = y + ky - 1;
            const int sx = xx + kx - 1;
            float4 v0 = make_float4(0.f, 0.f, 0.f, 0.f), v1 = v0;
            if (sy >= 0 && sy < HH && sx >= 0 && sx < WWW) {
                const float* src = x + ((((size_t)b * HH + sy) * WWW + sx) * IC + ic) * IP + ph;
                v0 = *(const float4*)(src);
                v1 = *(const float4*)(src + 4);
            }
            *(float4*)&u_lds[nl][ph] = v0;
            *(float4*)&u_lds[nl][ph + 4] = v1;
        }
    }

    float4 w[IP];
    {
        const float* wb = Wg + ((size_t)i * OC + c) * (IP * OP) + qq * 4;
#pragma unroll
        for (int p = 0; p < IP; ++p) w[p] = *(const float4*)(wb + p * OP);
    }
    __syncthreads();

    ushort_t* vb = votes + ((size_t)tileBase * NI + i) * CQ + c * OP + qq * 4;
    for (int nl = 0; nl < nC; ++nl) {
        const float4 u0 = *(const float4*)&u_lds[nl][0];
        const float4 u1 = *(const float4*)&u_lds[nl][4];
        const float4 u2 = *(const float4*)&u_lds[nl][8];
        const float4 u3 = *(const float4*)&u_lds[nl][12];
        float a0 = 0.f, a1 = 0.f, a2 = 0.f, a3 = 0.f;
#define ACC(uf, pp)                                         \
        a0 = fmaf(uf, w[pp].x, a0); a1 = fmaf(uf, w[pp].y, a1); \
        a2 = fmaf(uf, w[pp].z, a2); a3 = fmaf(uf, w[pp].w, a3);
        ACC(u0.x, 0)  ACC(u0.y, 1)  ACC(u0.z, 2)  ACC(u0.w, 3)
        ACC(u1.x, 4)  ACC(u1.y, 5)  ACC(u1.z, 6)  ACC(u1.w, 7)
        ACC(u2.x, 8)  ACC(u2.y, 9)  ACC(u2.z, 10) ACC(u2.w, 11)
        ACC(u3.x, 12) ACC(u3.y, 13) ACC(u3.z, 14) ACC(u3.w, 15)
#undef ACC
        ushort4 st;
        st.x = f2bf(a0); st.y = f2bf(a1); st.z = f2bf(a2); st.w = f2bf(a3);
        *(ushort4*)vb = st;
        vb += (size_t)NI * CQ;
    }
}

// ---------------------------------------------------------------------------
// Kernel B: DR routing, 2 streaming sweeps (sweep-0 replaced by s0_pre).
// Same proven 256-thread/48KB-LDS regime as R7 (VGPR 68, no spill); lg_lds
// kept both for logits and to anchor the 3-blocks/CU allocator target.
// ---------------------------------------------------------------------------
#define UNPACK16(A, B)                                                     \
    const float f0 = bf_lo(A.x), f1 = bf_hi(A.x), f2 = bf_lo(A.y),         \
                f3 = bf_hi(A.y), f4 = bf_lo(A.z), f5 = bf_hi(A.z),         \
                f6 = bf_lo(A.w), f7 = bf_hi(A.w), f8 = bf_lo(B.x),         \
                f9 = bf_hi(B.x), f10 = bf_lo(B.y), f11 = bf_hi(B.y),       \
                f12 = bf_lo(B.z), f13 = bf_hi(B.z), f14 = bf_lo(B.w),      \
                f15 = bf_hi(B.w);

__global__ __launch_bounds__(256) void route_kernel(
    const ushort_t* __restrict__ votes, const float* __restrict__ s0_pre,
    const float* __restrict__ bias, float* __restrict__ out, int nStart)
{
    __shared__ float lg_lds[NI * OC];     // 36 KB logits
    __shared__ float sPart[RWAVES][CQ];   // 8 KB
    __shared__ float s_sh[CQ];
    __shared__ float v_sh[CQ];
    __shared__ float fac_sh[OC];

    const int bn = blockIdx.x;
    const int t = threadIdx.x;
    const int wv = t >> 6;        // 0..3
    const int l = t & 63;
    const int isub = l >> 5;      // 0 / 1
    const int c = l & 31;
    const int iBase = 2 * wv + isub;   // 0..7; lane's i = iBase + 8*r

    const ushort_t* pbase = votes + (size_t)bn * NI * CQ + (size_t)iBase * CQ + c * OP;
    const size_t stepB = (size_t)8 * CQ;   // +8 i-rows per step

    // ---- phase 0: s0 from the precomputed GEMM (no vote read)
#pragma unroll
    for (int rep = 0; rep < 2; ++rep) {
        const int k = t + rep * 256;
        s_sh[k] = fmaf(s0_pre[(size_t)(nStart + bn) * CQ + k], 1.0f / OC, bias[k]);
    }
    __syncthreads();
    if (t < OC) {
        float sq = 0.f;
#pragma unroll
        for (int q = 0; q < OP; ++q) { const float s = s_sh[t * OP + q]; sq = fmaf(s, s, sq); }
        fac_sh[t] = (sq / (1.0f + sq)) * rsqrtf(sq + EPSQ);
    }
    __syncthreads();
#pragma unroll
    for (int rep = 0; rep < 2; ++rep) {
        const int k = t + rep * 256;
        v_sh[k] = s_sh[k] * fac_sh[k >> 4];
    }
    __syncthreads();

    float sa[16];
    float vr[16];

    // ---- 2 routed sweeps over the (L3-resident) votes
#pragma unroll
    for (int it = 0; it < 2; ++it) {
#pragma unroll
        for (int k = 0; k < 4; ++k) {
            const float4 v4 = *(const float4*)&v_sh[c * 16 + 4 * k];
            vr[4*k] = v4.x; vr[4*k+1] = v4.y; vr[4*k+2] = v4.z; vr[4*k+3] = v4.w;
        }
#pragma unroll
        for (int q = 0; q < 16; ++q) sa[q] = 0.f;
        uint4 A = ((const uint4*)pbase)[0];
        uint4 B = ((const uint4*)pbase)[1];
#pragma unroll 4
        for (int r = 0; r < RSTEPS; ++r) {
            uint4 An, Bn;
            if (r + 1 < RSTEPS) {
                const uint4* pn = (const uint4*)(pbase + (size_t)(r + 1) * stepB);
                An = pn[0]; Bn = pn[1];
            }
            UNPACK16(A, B)
            float a = f0 * vr[0];
            a = fmaf(f1, vr[1], a);   a = fmaf(f2, vr[2], a);   a = fmaf(f3, vr[3], a);
            a = fmaf(f4, vr[4], a);   a = fmaf(f5, vr[5], a);   a = fmaf(f6, vr[6], a);
            a = fmaf(f7, vr[7], a);   a = fmaf(f8, vr[8], a);   a = fmaf(f9, vr[9], a);
            a = fmaf(f10, vr[10], a); a = fmaf(f11, vr[11], a); a = fmaf(f12, vr[12], a);
            a = fmaf(f13, vr[13], a); a = fmaf(f14, vr[14], a); a = fmaf(f15, vr[15], a);
            const int li = (iBase + 8 * r) * OC + c;
            if (it == 0) lg_lds[li] = a;           // logits after iter 0
            else          a += lg_lds[li];          // accumulated logits
            const float e = __expf(a);              // |a| small: no max-sub needed
            float es = e;
            es += __shfl_xor(es, 1);
            es += __shfl_xor(es, 2);
            es += __shfl_xor(es, 4);
            es += __shfl_xor(es, 8);
            es += __shfl_xor(es, 16);
            const float coup = __fdividef(e, es);
            sa[0] = fmaf(coup, f0, sa[0]);   sa[1] = fmaf(coup, f1, sa[1]);
            sa[2] = fmaf(coup, f2, sa[2]);   sa[3] = fmaf(coup, f3, sa[3]);
            sa[4] = fmaf(coup, f4, sa[4]);   sa[5] = fmaf(coup, f5, sa[5]);
            sa[6] = fmaf(coup, f6, sa[6]);   sa[7] = fmaf(coup, f7, sa[7]);
            sa[8] = fmaf(coup, f8, sa[8]);   sa[9] = fmaf(coup, f9, sa[9]);
            sa[10] = fmaf(coup, f10, sa[10]); sa[11] = fmaf(coup, f11, sa[11]);
            sa[12] = fmaf(coup, f12, sa[12]); sa[13] = fmaf(coup, f13, sa[13]);
            sa[14] = fmaf(coup, f14, sa[14]); sa[15] = fmaf(coup, f15, sa[15]);
            A = An; B = Bn;
        }
#pragma unroll
        for (int q = 0; q < 16; ++q) sa[q] += __shfl_xor(sa[q], 32);
        if (isub == 0) {
#pragma unroll
            for (int k = 0; k < 4; ++k)
                *(float4*)&sPart[wv][c * 16 + 4 * k] = make_float4(sa[4*k], sa[4*k+1], sa[4*k+2], sa[4*k+3]);
        }
        __syncthreads();
#pragma unroll
        for (int rep = 0; rep < 2; ++rep) {
            const int k = t + rep * 256;
            float s = (sPart[0][k] + sPart[1][k]) + (sPart[2][k] + sPart[3][k]);
            s_sh[k] = s + bias[k];
        }
        __syncthreads();
        if (t < OC) {
            float sq = 0.f;
#pragma unroll
            for (int q = 0; q < OP; ++q) { const float s = s_sh[t * OP + q]; sq = fmaf(s, s, sq); }
            fac_sh[t] = (sq / (1.0f + sq)) * rsqrtf(sq + EPSQ);
        }
        __syncthreads();
#pragma unroll
        for (int rep = 0; rep < 2; ++rep) {
            const int k = t + rep * 256;
            v_sh[k] = s_sh[k] * fac_sh[k >> 4];
        }
        __syncthreads();
    }

#pragma unroll
    for (int rep = 0; rep < 2; ++rep) {
        const int k = t + rep * 256;
        out[(size_t)(nStart + bn) * CQ + k] = v_sh[k];
    }
}

// ---------------------------------------------------------------------------
extern "C" void kernel_launch(void* const* d_in, const int* in_sizes, int n_in,
                              void* d_out, int out_size, void* d_ws, size_t ws_size,
                              hipStream_t stream)
{
    const float* x = (const float*)d_in[0];
    const float* Wg = (const float*)d_in[1];
    const float* bias = (const float*)d_in[2];
    float* out = (float*)d_out;

    const size_t perN = (size_t)NI * CQ * sizeof(ushort_t);       // 294912 B/pixel
    const size_t packBytes = (size_t)NIP * 32 * 64 * 8 * 2;       // 4.72 MB
    const size_t s0Bytes = (size_t)NTOT * CQ * sizeof(float);     // 2.36 MB

    int chunk = 288;   // 84.9 MB votes: L3-resident for both routed sweeps
    if (ws_size < (size_t)chunk * perN + packBytes + s0Bytes) {
        size_t avail = (ws_size > packBytes + s0Bytes) ? ws_size - packBytes - s0Bytes : 0;
        chunk = (int)(avail / perN);
        if (chunk < 1) chunk = 1;
    }
    const size_t packOff = (size_t)chunk * perN;
    const size_t s0Off = packOff + packBytes;

    ushort_t* votes = (ushort_t*)d_ws;
    ushort_t* Wp = (ushort_t*)((char*)d_ws + packOff);
    float* s0_pre = (float*)((char*)d_ws + s0Off);

    hipLaunchKernelGGL(pack_kernel, dim3(NIP * 32), dim3(64), 0, stream, Wg, Wp);
    hipLaunchKernelGGL(s0_gemm_kernel, dim3(NTOT / 16, 4), dim3(64), 0, stream, x, Wp, s0_pre);

    for (int start = 0; start < NTOT; start += chunk) {
        const int cnt = (NTOT - start < chunk) ? (NTOT - start) : chunk;
        dim3 gA(NI, (cnt + 63) / 64);
        hipLaunchKernelGGL(votes_kernel, gA, dim3(128), 0, stream, x, Wg, votes, start, cnt);
        hipLaunchKernelGGL(route_kernel, dim3(cnt), dim3(256), 0, stream, votes, s0_pre, bias, out, start);
    }
}

// Round 9
// 260.806 us; speedup vs baseline: 1.3490x; 1.3490x over previous
//
#include <hip/hip_runtime.h>
#include <stdint.h>

typedef unsigned short ushort_t;

#define KK3 3
#define IC 32      // input capsules
#define IP 16      // input pose
#define OC 32      // output capsules
#define OP 16      // output pose
#define NI 288     // KK3*KK3*IC (im2col "i" dimension)
#define HH 12
#define WWW 12
#define NTOT 1152  // b*h*w
#define CQ 512     // OC*OP
#define EPSQ 1e-9f
#define RWAVES 4   // waves per route block (256 threads)
#define RSTEPS 36  // i-steps per lane: NI / 8 i-rows per step
#define NIP 144    // i-pairs (K-steps of 32 for the s0 GEMM)

typedef __attribute__((ext_vector_type(8))) short bf16x8;
typedef __attribute__((ext_vector_type(4))) float f32x4;

__device__ __forceinline__ float bf_lo(unsigned u) { return __uint_as_float(u << 16); }
__device__ __forceinline__ float bf_hi(unsigned u) { return __uint_as_float(u & 0xffff0000u); }
__device__ __forceinline__ ushort_t f2bf(float f) {
    unsigned u = __float_as_uint(f);
    return (ushort_t)((u + 0x7fffu + ((u >> 16) & 1u)) >> 16);   // RNE
}

// ---------------------------------------------------------------------------
// Kernel P: pack W (f32) -> bf16 in MFMA-B-fragment layout.  (unchanged, R8)
// Wp[ip][c][lane][8]: lane l holds W rows cq=c*16+q (q=l&15) at
// k = (l>>4)*8 + j; k<16 -> i=2*ip, k>=16 -> i=2*ip+1.
// ---------------------------------------------------------------------------
__global__ __launch_bounds__(64) void pack_kernel(
    const float* __restrict__ W, ushort_t* __restrict__ Wp)
{
    const int blk = blockIdx.x;          // ip*32 + c
    const int ip = blk >> 5;
    const int c = blk & 31;
    const int l = threadIdx.x;
    const int i = ip * 2 + ((l >> 5) & 1);
    const int p0 = ((l >> 4) & 1) * 8;
    const int q = l & 15;
    const float* src = W + (((size_t)(i * 32 + c) * 16 + p0) * 16 + q);
    union { ushort_t s[8]; uint4 u4; } o;
#pragma unroll
    for (int j = 0; j < 8; ++j) o.s[j] = f2bf(src[(size_t)j * 16]);
    *(uint4*)(Wp + ((size_t)blk * 64 + l) * 8) = o.u4;
}

// ---------------------------------------------------------------------------
// Kernel S (v2): s0_pre[n][cq] = sum_i votes[n,i,cq] via MFMA, K-split x4.
// grid = (72 px-tiles, 16 cq-blocks), block = 256 (4 waves).
// Wave wv handles ip in [wv*36, wv*36+36), computing 2 capsule-tiles;
// 8 KB LDS partial-reduce across the 4 waves. 1152 blocks = 18 waves/CU
// (R8's version was 1 wave/block, 288 blocks -> 1.1 wave/CU, 113 us,
// MfmaUtil 1.8% -- pure latency; this fixes the parallelism).
// ---------------------------------------------------------------------------
__global__ __launch_bounds__(256) void s0_gemm_kernel(
    const float* __restrict__ x, const ushort_t* __restrict__ Wp,
    float* __restrict__ s0_pre)
{
    __shared__ float red[4][512];        // 8 KB

    const int t = threadIdx.x;
    const int wv = t >> 6;
    const int l = t & 63;
    const int pxt = blockIdx.x;          // 0..71
    const int ctb = blockIdx.y * 2;      // capsule-tile base (0..31)
    const int px = pxt * 16 + (l & 15);
    const int b = px / (HH * WWW);
    const int rem = px % (HH * WWW);
    const int y = rem / WWW;
    const int xx = rem % WWW;
    const int ioff = (l >> 5) & 1;
    const int p0 = ((l >> 4) & 1) * 8;

    f32x4 acc0 = (f32x4){0.f, 0.f, 0.f, 0.f};
    f32x4 acc1 = (f32x4){0.f, 0.f, 0.f, 0.f};

    const int ip0 = wv * (NIP / 4);
    for (int k = 0; k < NIP / 4; ++k) {
        const int ip = ip0 + k;
        const int i = ip * 2 + ioff;
        const int ky = i / (KK3 * IC);
        const int kx = (i / IC) % KK3;
        const int ic = i & (IC - 1);
        const int sy = y + ky - 1;
        const int sx = xx + kx - 1;
        union { ushort_t s[8]; bf16x8 v; } ua;
        if (sy >= 0 && sy < HH && sx >= 0 && sx < WWW) {
            const float* s = x + ((((size_t)b * HH + sy) * WWW + sx) * IC + ic) * IP + p0;
            const float4 v0 = *(const float4*)s;
            const float4 v1 = *(const float4*)(s + 4);
            ua.s[0] = f2bf(v0.x); ua.s[1] = f2bf(v0.y); ua.s[2] = f2bf(v0.z); ua.s[3] = f2bf(v0.w);
            ua.s[4] = f2bf(v1.x); ua.s[5] = f2bf(v1.y); ua.s[6] = f2bf(v1.z); ua.s[7] = f2bf(v1.w);
        } else {
#pragma unroll
            for (int j = 0; j < 8; ++j) ua.s[j] = 0;
        }
        const bf16x8 b0 = *(const bf16x8*)(Wp + (((size_t)ip * 32 + ctb) * 64 + l) * 8);
        const bf16x8 b1 = *(const bf16x8*)(Wp + (((size_t)ip * 32 + ctb + 1) * 64 + l) * 8);
        acc0 = __builtin_amdgcn_mfma_f32_16x16x32_bf16(ua.v, b0, acc0, 0, 0, 0);
        acc1 = __builtin_amdgcn_mfma_f32_16x16x32_bf16(ua.v, b1, acc1, 0, 0, 0);
    }

    {
        const int row = (l >> 4) * 4;
        const int col = l & 15;
#pragma unroll
        for (int r = 0; r < 4; ++r) {
            red[wv][(row + r) * 16 + col] = acc0[r];
            red[wv][256 + (row + r) * 16 + col] = acc1[r];
        }
    }
    __syncthreads();
#pragma unroll
    for (int rep = 0; rep < 2; ++rep) {
        const int k = t + rep * 256;                    // 0..511
        const float v = (red[0][k] + red[1][k]) + (red[2][k] + red[3][k]);
        const int ct = k >> 8;
        const int row = (k >> 4) & 15;
        const int col = k & 15;
        s0_pre[(size_t)(pxt * 16 + row) * CQ + (size_t)(ctb + ct) * 16 + col] = v;
    }
}

// ---------------------------------------------------------------------------
// Kernel A: votes[nl][i][c][q] (bf16) for one pixel chunk.  (unchanged, R7)
// ---------------------------------------------------------------------------
__global__ __launch_bounds__(128) void votes_kernel(
    const float* __restrict__ x, const float* __restrict__ Wg,
    ushort_t* __restrict__ votes, int nStart, int nCount)
{
    __shared__ float u_lds[64][IP];

    const int i = blockIdx.x;
    const int tileBase = blockIdx.y * 64;
    const int nC = min(64, nCount - tileBase);
    const int t = threadIdx.x;
    const int c = t >> 2;
    const int qq = t & 3;

    const int ky = i / (KK3 * IC);
    const int kx = (i / IC) % KK3;
    const int ic = i % IC;

    {
        const int nl = t >> 1;
        const int ph = (t & 1) * 8;
        if (nl < nC) {
            const int n = nStart + tileBase + nl;
            const int b = n / (HH * WWW);
            const int rem = n % (HH * WWW);
            const int y = rem / WWW;
            const int xx = rem % WWW;
            const int sy = y + ky - 1;
            const int sx = xx + kx - 1;
            float4 v0 = make_float4(0.f, 0.f, 0.f, 0.f), v1 = v0;
            if (sy >= 0 && sy < HH && sx >= 0 && sx < WWW) {
                const float* src = x + ((((size_t)b * HH + sy) * WWW + sx) * IC + ic) * IP + ph;
                v0 = *(const float4*)(src);
                v1 = *(const float4*)(src + 4);
            }
            *(float4*)&u_lds[nl][ph] = v0;
            *(float4*)&u_lds[nl][ph + 4] = v1;
        }
    }

    float4 w[IP];
    {
        const float* wb = Wg + ((size_t)i * OC + c) * (IP * OP) + qq * 4;
#pragma unroll
        for (int p = 0; p < IP; ++p) w[p] = *(const float4*)(wb + p * OP);
    }
    __syncthreads();

    ushort_t* vb = votes + ((size_t)tileBase * NI + i) * CQ + c * OP + qq * 4;
    for (int nl = 0; nl < nC; ++nl) {
        const float4 u0 = *(const float4*)&u_lds[nl][0];
        const float4 u1 = *(const float4*)&u_lds[nl][4];
        const float4 u2 = *(const float4*)&u_lds[nl][8];
        const float4 u3 = *(const float4*)&u_lds[nl][12];
        float a0 = 0.f, a1 = 0.f, a2 = 0.f, a3 = 0.f;
#define ACC(uf, pp)                                         \
        a0 = fmaf(uf, w[pp].x, a0); a1 = fmaf(uf, w[pp].y, a1); \
        a2 = fmaf(uf, w[pp].z, a2); a3 = fmaf(uf, w[pp].w, a3);
        ACC(u0.x, 0)  ACC(u0.y, 1)  ACC(u0.z, 2)  ACC(u0.w, 3)
        ACC(u1.x, 4)  ACC(u1.y, 5)  ACC(u1.z, 6)  ACC(u1.w, 7)
        ACC(u2.x, 8)  ACC(u2.y, 9)  ACC(u2.z, 10) ACC(u2.w, 11)
        ACC(u3.x, 12) ACC(u3.y, 13) ACC(u3.z, 14) ACC(u3.w, 15)
#undef ACC
        ushort4 st;
        st.x = f2bf(a0); st.y = f2bf(a1); st.z = f2bf(a2); st.w = f2bf(a3);
        *(ushort4*)vb = st;
        vb += (size_t)NI * CQ;
    }
}

// ---------------------------------------------------------------------------
// Kernel B: DR routing, 2 streaming sweeps (sweep-0 from s0_pre), 3-deep
// register prefetch ring (was 1-deep; route was latency-bound: VALUBusy 25%).
// Same proven 256-thread/48KB-LDS allocator regime as R7 (no spill at ~84
// live VGPRs; regime grants what's needed, R1/R7 evidence).
// ---------------------------------------------------------------------------
#define UNPACK16(A, B)                                                     \
    const float f0 = bf_lo(A.x), f1 = bf_hi(A.x), f2 = bf_lo(A.y),         \
                f3 = bf_hi(A.y), f4 = bf_lo(A.z), f5 = bf_hi(A.z),         \
                f6 = bf_lo(A.w), f7 = bf_hi(A.w), f8 = bf_lo(B.x),         \
                f9 = bf_hi(B.x), f10 = bf_lo(B.y), f11 = bf_hi(B.y),       \
                f12 = bf_lo(B.z), f13 = bf_hi(B.z), f14 = bf_lo(B.w),      \
                f15 = bf_hi(B.w);

__global__ __launch_bounds__(256) void route_kernel(
    const ushort_t* __restrict__ votes, const float* __restrict__ s0_pre,
    const float* __restrict__ bias, float* __restrict__ out, int nStart)
{
    __shared__ float lg_lds[NI * OC];     // 36 KB logits
    __shared__ float sPart[RWAVES][CQ];   // 8 KB
    __shared__ float s_sh[CQ];
    __shared__ float v_sh[CQ];
    __shared__ float fac_sh[OC];

    const int bn = blockIdx.x;
    const int t = threadIdx.x;
    const int wv = t >> 6;        // 0..3
    const int l = t & 63;
    const int isub = l >> 5;      // 0 / 1
    const int c = l & 31;
    const int iBase = 2 * wv + isub;   // 0..7; lane's i = iBase + 8*r

    const ushort_t* pbase = votes + (size_t)bn * NI * CQ + (size_t)iBase * CQ + c * OP;
    const size_t stepB = (size_t)8 * CQ;   // +8 i-rows per step

    // ---- phase 0: s0 from the precomputed GEMM (no vote read)
#pragma unroll
    for (int rep = 0; rep < 2; ++rep) {
        const int k = t + rep * 256;
        s_sh[k] = fmaf(s0_pre[(size_t)(nStart + bn) * CQ + k], 1.0f / OC, bias[k]);
    }
    __syncthreads();
    if (t < OC) {
        float sq = 0.f;
#pragma unroll
        for (int q = 0; q < OP; ++q) { const float s = s_sh[t * OP + q]; sq = fmaf(s, s, sq); }
        fac_sh[t] = (sq / (1.0f + sq)) * rsqrtf(sq + EPSQ);
    }
    __syncthreads();
#pragma unroll
    for (int rep = 0; rep < 2; ++rep) {
        const int k = t + rep * 256;
        v_sh[k] = s_sh[k] * fac_sh[k >> 4];
    }
    __syncthreads();

    float sa[16];
    float vr[16];

#define RBODY(AA, BB, rr)                                                   \
        {                                                                   \
            UNPACK16(AA, BB)                                                \
            float a = f0 * vr[0];                                           \
            a = fmaf(f1, vr[1], a);   a = fmaf(f2, vr[2], a);               \
            a = fmaf(f3, vr[3], a);   a = fmaf(f4, vr[4], a);               \
            a = fmaf(f5, vr[5], a);   a = fmaf(f6, vr[6], a);               \
            a = fmaf(f7, vr[7], a);   a = fmaf(f8, vr[8], a);               \
            a = fmaf(f9, vr[9], a);   a = fmaf(f10, vr[10], a);             \
            a = fmaf(f11, vr[11], a); a = fmaf(f12, vr[12], a);             \
            a = fmaf(f13, vr[13], a); a = fmaf(f14, vr[14], a);             \
            a = fmaf(f15, vr[15], a);                                       \
            const int li = (iBase + 8 * (rr)) * OC + c;                     \
            if (it == 0) lg_lds[li] = a;                                    \
            else          a += lg_lds[li];                                  \
            const float e = __expf(a);                                      \
            float es = e;                                                   \
            es += __shfl_xor(es, 1);                                        \
            es += __shfl_xor(es, 2);                                        \
            es += __shfl_xor(es, 4);                                        \
            es += __shfl_xor(es, 8);                                        \
            es += __shfl_xor(es, 16);                                       \
            const float coup = __fdividef(e, es);                           \
            sa[0] = fmaf(coup, f0, sa[0]);   sa[1] = fmaf(coup, f1, sa[1]); \
            sa[2] = fmaf(coup, f2, sa[2]);   sa[3] = fmaf(coup, f3, sa[3]); \
            sa[4] = fmaf(coup, f4, sa[4]);   sa[5] = fmaf(coup, f5, sa[5]); \
            sa[6] = fmaf(coup, f6, sa[6]);   sa[7] = fmaf(coup, f7, sa[7]); \
            sa[8] = fmaf(coup, f8, sa[8]);   sa[9] = fmaf(coup, f9, sa[9]); \
            sa[10] = fmaf(coup, f10, sa[10]); sa[11] = fmaf(coup, f11, sa[11]); \
            sa[12] = fmaf(coup, f12, sa[12]); sa[13] = fmaf(coup, f13, sa[13]); \
            sa[14] = fmaf(coup, f14, sa[14]); sa[15] = fmaf(coup, f15, sa[15]); \
        }
#define RPREF(AA, BB, rn)                                                   \
        if ((rn) < RSTEPS) {                                                \
            const uint4* pn = (const uint4*)(pbase + (size_t)(rn) * stepB); \
            AA = pn[0]; BB = pn[1];                                         \
        }

    // ---- 2 routed sweeps over the (L3-resident) votes
#pragma unroll
    for (int it = 0; it < 2; ++it) {
#pragma unroll
        for (int k = 0; k < 4; ++k) {
            const float4 v4 = *(const float4*)&v_sh[c * 16 + 4 * k];
            vr[4*k] = v4.x; vr[4*k+1] = v4.y; vr[4*k+2] = v4.z; vr[4*k+3] = v4.w;
        }
#pragma unroll
        for (int q = 0; q < 16; ++q) sa[q] = 0.f;

        uint4 A0, B0, A1, B1, A2, B2;
        RPREF(A0, B0, 0)
        RPREF(A1, B1, 1)
        RPREF(A2, B2, 2)
        for (int r = 0; r < RSTEPS; r += 3) {
            RBODY(A0, B0, r)     RPREF(A0, B0, r + 3)
            RBODY(A1, B1, r + 1) RPREF(A1, B1, r + 4)
            RBODY(A2, B2, r + 2) RPREF(A2, B2, r + 5)
        }

#pragma unroll
        for (int q = 0; q < 16; ++q) sa[q] += __shfl_xor(sa[q], 32);
        if (isub == 0) {
#pragma unroll
            for (int k = 0; k < 4; ++k)
                *(float4*)&sPart[wv][c * 16 + 4 * k] = make_float4(sa[4*k], sa[4*k+1], sa[4*k+2], sa[4*k+3]);
        }
        __syncthreads();
#pragma unroll
        for (int rep = 0; rep < 2; ++rep) {
            const int k = t + rep * 256;
            float s = (sPart[0][k] + sPart[1][k]) + (sPart[2][k] + sPart[3][k]);
            s_sh[k] = s + bias[k];
        }
        __syncthreads();
        if (t < OC) {
            float sq = 0.f;
#pragma unroll
            for (int q = 0; q < OP; ++q) { const float s = s_sh[t * OP + q]; sq = fmaf(s, s, sq); }
            fac_sh[t] = (sq / (1.0f + sq)) * rsqrtf(sq + EPSQ);
        }
        __syncthreads();
#pragma unroll
        for (int rep = 0; rep < 2; ++rep) {
            const int k = t + rep * 256;
            v_sh[k] = s_sh[k] * fac_sh[k >> 4];
        }
        __syncthreads();
    }

#pragma unroll
    for (int rep = 0; rep < 2; ++rep) {
        const int k = t + rep * 256;
        out[(size_t)(nStart + bn) * CQ + k] = v_sh[k];
    }
}

// ---------------------------------------------------------------------------
extern "C" void kernel_launch(void* const* d_in, const int* in_sizes, int n_in,
                              void* d_out, int out_size, void* d_ws, size_t ws_size,
                              hipStream_t stream)
{
    const float* x = (const float*)d_in[0];
    const float* Wg = (const float*)d_in[1];
    const float* bias = (const float*)d_in[2];
    float* out = (float*)d_out;

    const size_t perN = (size_t)NI * CQ * sizeof(ushort_t);       // 294912 B/pixel
    const size_t packBytes = (size_t)NIP * 32 * 64 * 8 * 2;       // 4.72 MB
    const size_t s0Bytes = (size_t)NTOT * CQ * sizeof(float);     // 2.36 MB

    int chunk = 576;   // 169 MB votes: L3-resident for both routed sweeps
    if (ws_size < (size_t)chunk * perN + packBytes + s0Bytes) {
        size_t avail = (ws_size > packBytes + s0Bytes) ? ws_size - packBytes - s0Bytes : 0;
        chunk = (int)(avail / perN);
        if (chunk < 1) chunk = 1;
    }
    const size_t packOff = (size_t)chunk * perN;
    const size_t s0Off = packOff + packBytes;

    ushort_t* votes = (ushort_t*)d_ws;
    ushort_t* Wp = (ushort_t*)((char*)d_ws + packOff);
    float* s0_pre = (float*)((char*)d_ws + s0Off);

    hipLaunchKernelGGL(pack_kernel, dim3(NIP * 32), dim3(64), 0, stream, Wg, Wp);
    hipLaunchKernelGGL(s0_gemm_kernel, dim3(NTOT / 16, 16), dim3(256), 0, stream, x, Wp, s0_pre);

    for (int start = 0; start < NTOT; start += chunk) {
        const int cnt = (NTOT - start < chunk) ? (NTOT - start) : chunk;
        dim3 gA(NI, (cnt + 63) / 64);
        hipLaunchKernelGGL(votes_kernel, gA, dim3(128), 0, stream, x, Wg, votes, start, cnt);
        hipLaunchKernelGGL(route_kernel, dim3(cnt), dim3(256), 0, stream, votes, s0_pre, bias, out, start);
    }
}

// Round 10
// 215.002 us; speedup vs baseline: 1.6364x; 1.2130x over previous
//
#include <hip/hip_runtime.h>
#include <stdint.h>

typedef unsigned short ushort_t;

#define KK3 3
#define IC 32      // input capsules
#define IP 16      // input pose
#define OC 32      // output capsules
#define OP 16      // output pose
#define NI 288     // KK3*KK3*IC (im2col "i" dimension)
#define HH 12
#define WWW 12
#define NTOT 1152  // b*h*w
#define CQ 512     // OC*OP
#define EPSQ 1e-9f
#define RWAVES 4   // waves per route block (256 threads)
#define RSTEPS 36  // route i-steps per lane
#define NIP 144    // i-pairs (K=32 MFMA steps)
#define NIG 18     // i-groups for votes_s0 (16 i = 8 pairs each)
#define IPG 8      // pairs per i-group

typedef __attribute__((ext_vector_type(8))) short bf16x8;
typedef __attribute__((ext_vector_type(4))) float f32x4;

__device__ __forceinline__ float bf_lo(unsigned u) { return __uint_as_float(u << 16); }
__device__ __forceinline__ float bf_hi(unsigned u) { return __uint_as_float(u & 0xffff0000u); }
__device__ __forceinline__ ushort_t f2bf(float f) {
    unsigned u = __float_as_uint(f);
    return (ushort_t)((u + 0x7fffu + ((u >> 16) & 1u)) >> 16);   // RNE
}

// ---------------------------------------------------------------------------
// Kernel P: pack W (f32) -> bf16 in MFMA-B-fragment layout.  (unchanged, R8)
// Wp[ip][c][lane][8]: lane l holds cols q=l&15 at k=(l>>4)*8+j;
// k<16 -> i=2*ip (p=k), k>=16 -> i=2*ip+1 (p=k-16).
// ---------------------------------------------------------------------------
__global__ __launch_bounds__(64) void pack_kernel(
    const float* __restrict__ W, ushort_t* __restrict__ Wp)
{
    const int blk = blockIdx.x;          // ip*32 + c
    const int ip = blk >> 5;
    const int c = blk & 31;
    const int l = threadIdx.x;
    const int i = ip * 2 + ((l >> 5) & 1);
    const int p0 = ((l >> 4) & 1) * 8;
    const int q = l & 15;
    const float* src = W + (((size_t)(i * 32 + c) * 16 + p0) * 16 + q);
    union { ushort_t s[8]; uint4 u4; } o;
#pragma unroll
    for (int j = 0; j < 8; ++j) o.s[j] = f2bf(src[(size_t)j * 16]);
    *(uint4*)(Wp + ((size_t)blk * 64 + l) * 8) = o.u4;
}

// ---------------------------------------------------------------------------
// Kernel V: votes (bf16, layout [n][i][cq] -- unchanged for route) AND s0
// partials, all via MFMA. grid = (cnt/16 px-tiles, 18 i-groups), block 256.
// Zero-masking trick: per i-pair, ONE Wp frag gives three MFMAs --
//   B_even (lanes k<16 keep, k>=16 zero) -> exact votes of i_even,
//   B_odd  (inverse mask)                -> exact votes of i_odd,
//   full frag accumulated                -> s0 partial (sum over the pair).
// D tiles staged in a 64KB f32 LDS slab -> coalesced 16B bf16 stores.
// LDS 64KB => 2 blocks/CU => 2 waves/SIMD => 256-VGPR budget (need ~80):
// spill-impossible by construction (the R2-R6 allocator lesson).
// ---------------------------------------------------------------------------
__global__ __launch_bounds__(256) void votes_s0_kernel(
    const float* __restrict__ x, const ushort_t* __restrict__ Wp,
    ushort_t* __restrict__ votes, float* __restrict__ s0_part,
    int nStart, int nCount)
{
    __shared__ float slab[2][16][CQ];    // 64 KB staging (even / odd i)

    const int t = threadIdx.x;
    const int w = t >> 6;                // wave 0..3: owns ct = w*8 .. +8
    const int l = t & 63;
    const int pxt = blockIdx.x;
    const int ig = blockIdx.y;

    // A-frag geometry (identical to R9's verified s0_gemm)
    const int n = nStart + pxt * 16 + (l & 15);
    const int b = n / (HH * WWW);
    const int rem = n % (HH * WWW);
    const int y = rem / WWW;
    const int xx = rem % WWW;
    const int ioff = (l >> 5) & 1;
    const int p0 = ((l >> 4) & 1) * 8;

    const bf16x8 z8 = {0, 0, 0, 0, 0, 0, 0, 0};
    const f32x4 z4 = {0.f, 0.f, 0.f, 0.f};

    f32x4 accs0[8];
#pragma unroll
    for (int ctl = 0; ctl < 8; ++ctl) accs0[ctl] = z4;

    for (int m = 0; m < IPG; ++m) {
        const int ip = ig * IPG + m;     // global i-pair
        // ---- A-frag: u for this lane's i = 2*ip + ioff, p = p0..p0+7
        union { ushort_t s[8]; bf16x8 v; } ua;
        {
            const int i = ip * 2 + ioff;
            const int ky = i / (KK3 * IC);
            const int kx = (i / IC) % KK3;
            const int ic = i & (IC - 1);
            const int sy = y + ky - 1;
            const int sx = xx + kx - 1;
            if (sy >= 0 && sy < HH && sx >= 0 && sx < WWW) {
                const float* s = x + ((((size_t)b * HH + sy) * WWW + sx) * IC + ic) * IP + p0;
                const float4 v0 = *(const float4*)s;
                const float4 v1 = *(const float4*)(s + 4);
                ua.s[0] = f2bf(v0.x); ua.s[1] = f2bf(v0.y); ua.s[2] = f2bf(v0.z); ua.s[3] = f2bf(v0.w);
                ua.s[4] = f2bf(v1.x); ua.s[5] = f2bf(v1.y); ua.s[6] = f2bf(v1.z); ua.s[7] = f2bf(v1.w);
            } else {
#pragma unroll
                for (int j = 0; j < 8; ++j) ua.s[j] = 0;
            }
        }
        // ---- 8 c-tiles per wave: 3 MFMAs per (pair, ct)
        const int q = l & 15;
        const int r0 = (l >> 4) * 4;
#pragma unroll
        for (int ctl = 0; ctl < 8; ++ctl) {
            const int ct = w * 8 + ctl;
            const bf16x8 frag = *(const bf16x8*)(Wp + (((size_t)ip * 32 + ct) * 64 + l) * 8);
            const bf16x8 be = (l < 32) ? frag : z8;   // keep k<16  -> i_even
            const bf16x8 bo = (l < 32) ? z8 : frag;   // keep k>=16 -> i_odd
            const f32x4 ve = __builtin_amdgcn_mfma_f32_16x16x32_bf16(ua.v, be, z4, 0, 0, 0);
            const f32x4 vo = __builtin_amdgcn_mfma_f32_16x16x32_bf16(ua.v, bo, z4, 0, 0, 0);
            accs0[ctl] = __builtin_amdgcn_mfma_f32_16x16x32_bf16(ua.v, frag, accs0[ctl], 0, 0, 0);
            const int col = ct * 16 + q;
#pragma unroll
            for (int r = 0; r < 4; ++r) {
                slab[0][r0 + r][col] = ve[r];
                slab[1][r0 + r][col] = vo[r];
            }
        }
        __syncthreads();
        // ---- coalesced writeout of both slabs as bf16 votes
        {
            const int px = t >> 4;           // 0..15
            const int ch0 = t & 15;          // 16B-chunk base (chunks of 8 bf16)
            const int nl = pxt * 16 + px;    // chunk-local pixel
#pragma unroll
            for (int s = 0; s < 2; ++s) {
                ushort_t* dst = votes + ((size_t)nl * NI + (2 * ip + s)) * CQ;
#pragma unroll
                for (int cc = 0; cc < 4; ++cc) {
                    const int ch = ch0 + cc * 16;         // 0..63
                    const float* sp = &slab[s][px][ch * 8];
                    const float4 f0 = *(const float4*)sp;
                    const float4 f1 = *(const float4*)(sp + 4);
                    union { ushort_t s8[8]; uint4 u4; } o;
                    o.s8[0] = f2bf(f0.x); o.s8[1] = f2bf(f0.y); o.s8[2] = f2bf(f0.z); o.s8[3] = f2bf(f0.w);
                    o.s8[4] = f2bf(f1.x); o.s8[5] = f2bf(f1.y); o.s8[6] = f2bf(f1.z); o.s8[7] = f2bf(f1.w);
                    *(uint4*)(dst + ch * 8) = o.u4;
                }
            }
        }
        __syncthreads();
    }

    // ---- s0 partials: accs0 holds sum of votes over this block's 16 i
    {
        const int q = l & 15;
        const int r0 = (l >> 4) * 4;
#pragma unroll
        for (int ctl = 0; ctl < 8; ++ctl) {
            const int cq = (w * 8 + ctl) * 16 + q;
#pragma unroll
            for (int r = 0; r < 4; ++r)
                s0_part[((size_t)ig * nCount + pxt * 16 + r0 + r) * CQ + cq] = accs0[ctl][r];
        }
    }
}

// ---------------------------------------------------------------------------
// Kernel F: s0_pre[n][cq] = sum over 18 i-group partials.
// ---------------------------------------------------------------------------
__global__ __launch_bounds__(256) void s0_fin_kernel(
    const float* __restrict__ s0_part, float* __restrict__ s0_pre,
    int nStart, int nCount)
{
    const int bn = blockIdx.x;
    const int t = threadIdx.x;
#pragma unroll
    for (int rep = 0; rep < 2; ++rep) {
        const int k = t + rep * 256;
        float s = 0.f;
#pragma unroll
        for (int g = 0; g < NIG; ++g)
            s += s0_part[((size_t)g * nCount + bn) * CQ + k];
        s0_pre[(size_t)(nStart + bn) * CQ + k] = s;
    }
}

// ---------------------------------------------------------------------------
// Kernel B: DR routing (unchanged from R9 -- proven: VGPR 68, no spill).
// ---------------------------------------------------------------------------
#define UNPACK16(A, B)                                                     \
    const float f0 = bf_lo(A.x), f1 = bf_hi(A.x), f2 = bf_lo(A.y),         \
                f3 = bf_hi(A.y), f4 = bf_lo(A.z), f5 = bf_hi(A.z),         \
                f6 = bf_lo(A.w), f7 = bf_hi(A.w), f8 = bf_lo(B.x),         \
                f9 = bf_hi(B.x), f10 = bf_lo(B.y), f11 = bf_hi(B.y),       \
                f12 = bf_lo(B.z), f13 = bf_hi(B.z), f14 = bf_lo(B.w),      \
                f15 = bf_hi(B.w);

__global__ __launch_bounds__(256) void route_kernel(
    const ushort_t* __restrict__ votes, const float* __restrict__ s0_pre,
    const float* __restrict__ bias, float* __restrict__ out, int nStart)
{
    __shared__ float lg_lds[NI * OC];     // 36 KB logits
    __shared__ float sPart[RWAVES][CQ];   // 8 KB
    __shared__ float s_sh[CQ];
    __shared__ float v_sh[CQ];
    __shared__ float fac_sh[OC];

    const int bn = blockIdx.x;
    const int t = threadIdx.x;
    const int wv = t >> 6;
    const int l = t & 63;
    const int isub = l >> 5;
    const int c = l & 31;
    const int iBase = 2 * wv + isub;

    const ushort_t* pbase = votes + (size_t)bn * NI * CQ + (size_t)iBase * CQ + c * OP;
    const size_t stepB = (size_t)8 * CQ;

    // ---- phase 0: s0 from the precomputed sum
#pragma unroll
    for (int rep = 0; rep < 2; ++rep) {
        const int k = t + rep * 256;
        s_sh[k] = fmaf(s0_pre[(size_t)(nStart + bn) * CQ + k], 1.0f / OC, bias[k]);
    }
    __syncthreads();
    if (t < OC) {
        float sq = 0.f;
#pragma unroll
        for (int q = 0; q < OP; ++q) { const float s = s_sh[t * OP + q]; sq = fmaf(s, s, sq); }
        fac_sh[t] = (sq / (1.0f + sq)) * rsqrtf(sq + EPSQ);
    }
    __syncthreads();
#pragma unroll
    for (int rep = 0; rep < 2; ++rep) {
        const int k = t + rep * 256;
        v_sh[k] = s_sh[k] * fac_sh[k >> 4];
    }
    __syncthreads();

    float sa[16];
    float vr[16];

#define RBODY(AA, BB, rr)                                                   \
        {                                                                   \
            UNPACK16(AA, BB)                                                \
            float a = f0 * vr[0];                                           \
            a = fmaf(f1, vr[1], a);   a = fmaf(f2, vr[2], a);               \
            a = fmaf(f3, vr[3], a);   a = fmaf(f4, vr[4], a);               \
            a = fmaf(f5, vr[5], a);   a = fmaf(f6, vr[6], a);               \
            a = fmaf(f7, vr[7], a);   a = fmaf(f8, vr[8], a);               \
            a = fmaf(f9, vr[9], a);   a = fmaf(f10, vr[10], a);             \
            a = fmaf(f11, vr[11], a); a = fmaf(f12, vr[12], a);             \
            a = fmaf(f13, vr[13], a); a = fmaf(f14, vr[14], a);             \
            a = fmaf(f15, vr[15], a);                                       \
            const int li = (iBase + 8 * (rr)) * OC + c;                     \
            if (it == 0) lg_lds[li] = a;                                    \
            else          a += lg_lds[li];                                  \
            const float e = __expf(a);                                      \
            float es = e;                                                   \
            es += __shfl_xor(es, 1);                                        \
            es += __shfl_xor(es, 2);                                        \
            es += __shfl_xor(es, 4);                                        \
            es += __shfl_xor(es, 8);                                        \
            es += __shfl_xor(es, 16);                                       \
            const float coup = __fdividef(e, es);                           \
            sa[0] = fmaf(coup, f0, sa[0]);   sa[1] = fmaf(coup, f1, sa[1]); \
            sa[2] = fmaf(coup, f2, sa[2]);   sa[3] = fmaf(coup, f3, sa[3]); \
            sa[4] = fmaf(coup, f4, sa[4]);   sa[5] = fmaf(coup, f5, sa[5]); \
            sa[6] = fmaf(coup, f6, sa[6]);   sa[7] = fmaf(coup, f7, sa[7]); \
            sa[8] = fmaf(coup, f8, sa[8]);   sa[9] = fmaf(coup, f9, sa[9]); \
            sa[10] = fmaf(coup, f10, sa[10]); sa[11] = fmaf(coup, f11, sa[11]); \
            sa[12] = fmaf(coup, f12, sa[12]); sa[13] = fmaf(coup, f13, sa[13]); \
            sa[14] = fmaf(coup, f14, sa[14]); sa[15] = fmaf(coup, f15, sa[15]); \
        }
#define RPREF(AA, BB, rn)                                                   \
        if ((rn) < RSTEPS) {                                                \
            const uint4* pn = (const uint4*)(pbase + (size_t)(rn) * stepB); \
            AA = pn[0]; BB = pn[1];                                         \
        }

#pragma unroll
    for (int it = 0; it < 2; ++it) {
#pragma unroll
        for (int k = 0; k < 4; ++k) {
            const float4 v4 = *(const float4*)&v_sh[c * 16 + 4 * k];
            vr[4*k] = v4.x; vr[4*k+1] = v4.y; vr[4*k+2] = v4.z; vr[4*k+3] = v4.w;
        }
#pragma unroll
        for (int q = 0; q < 16; ++q) sa[q] = 0.f;

        uint4 A0, B0, A1, B1, A2, B2;
        RPREF(A0, B0, 0)
        RPREF(A1, B1, 1)
        RPREF(A2, B2, 2)
        for (int r = 0; r < RSTEPS; r += 3) {
            RBODY(A0, B0, r)     RPREF(A0, B0, r + 3)
            RBODY(A1, B1, r + 1) RPREF(A1, B1, r + 4)
            RBODY(A2, B2, r + 2) RPREF(A2, B2, r + 5)
        }

#pragma unroll
        for (int q = 0; q < 16; ++q) sa[q] += __shfl_xor(sa[q], 32);
        if (isub == 0) {
#pragma unroll
            for (int k = 0; k < 4; ++k)
                *(float4*)&sPart[wv][c * 16 + 4 * k] = make_float4(sa[4*k], sa[4*k+1], sa[4*k+2], sa[4*k+3]);
        }
        __syncthreads();
#pragma unroll
        for (int rep = 0; rep < 2; ++rep) {
            const int k = t + rep * 256;
            float s = (sPart[0][k] + sPart[1][k]) + (sPart[2][k] + sPart[3][k]);
            s_sh[k] = s + bias[k];
        }
        __syncthreads();
        if (t < OC) {
            float sq = 0.f;
#pragma unroll
            for (int q = 0; q < OP; ++q) { const float s = s_sh[t * OP + q]; sq = fmaf(s, s, sq); }
            fac_sh[t] = (sq / (1.0f + sq)) * rsqrtf(sq + EPSQ);
        }
        __syncthreads();
#pragma unroll
        for (int rep = 0; rep < 2; ++rep) {
            const int k = t + rep * 256;
            v_sh[k] = s_sh[k] * fac_sh[k >> 4];
        }
        __syncthreads();
    }

#pragma unroll
    for (int rep = 0; rep < 2; ++rep) {
        const int k = t + rep * 256;
        out[(size_t)(nStart + bn) * CQ + k] = v_sh[k];
    }
}

// ---------------------------------------------------------------------------
extern "C" void kernel_launch(void* const* d_in, const int* in_sizes, int n_in,
                              void* d_out, int out_size, void* d_ws, size_t ws_size,
                              hipStream_t stream)
{
    const float* x = (const float*)d_in[0];
    const float* Wg = (const float*)d_in[1];
    const float* bias = (const float*)d_in[2];
    float* out = (float*)d_out;

    const size_t perN = (size_t)NI * CQ * sizeof(ushort_t);       // 294912 B/pixel
    const size_t packBytes = (size_t)NIP * 32 * 64 * 8 * 2;       // 4.72 MB
    const size_t s0Bytes = (size_t)NTOT * CQ * sizeof(float);     // 2.36 MB
    const size_t perNpart = (size_t)NIG * CQ * sizeof(float);     // 36.9 KB/pixel partials

    int chunk = 768;   // 226 MB votes: L3-resident, route grid = 3 blocks/CU
    if (ws_size < (size_t)chunk * (perN + perNpart) + packBytes + s0Bytes) {
        size_t avail = (ws_size > packBytes + s0Bytes) ? ws_size - packBytes - s0Bytes : 0;
        chunk = (int)(avail / (perN + perNpart));
        chunk &= ~15;
        if (chunk < 16) chunk = 16;
    }
    const size_t packOff = (size_t)chunk * perN;
    const size_t s0Off = packOff + packBytes;
    const size_t partOff = s0Off + s0Bytes;

    ushort_t* votes = (ushort_t*)d_ws;
    ushort_t* Wp = (ushort_t*)((char*)d_ws + packOff);
    float* s0_pre = (float*)((char*)d_ws + s0Off);
    float* s0_part = (float*)((char*)d_ws + partOff);

    hipLaunchKernelGGL(pack_kernel, dim3(NIP * 32), dim3(64), 0, stream, Wg, Wp);

    for (int start = 0; start < NTOT; start += chunk) {
        const int cnt = (NTOT - start < chunk) ? (NTOT - start) : chunk;
        hipLaunchKernelGGL(votes_s0_kernel, dim3(cnt / 16, NIG), dim3(256), 0, stream,
                           x, Wp, votes, s0_part, start, cnt);
        hipLaunchKernelGGL(s0_fin_kernel, dim3(cnt), dim3(256), 0, stream,
                           s0_part, s0_pre, start, cnt);
        hipLaunchKernelGGL(route_kernel, dim3(cnt), dim3(256), 0, stream,
                           votes, s0_pre, bias, out, start);
    }
}